// Round 8
// baseline (361.175 us; speedup 1.0000x reference)
//
#include <hip/hip_runtime.h>
#include <float.h>

// Shapes (fixed by the problem)
#define Bsz 2
#define Ssz 4096
#define Hsz 12
#define Gsz 64
#define Wsz 513            // W_LOC
#define Csz (Gsz + Wsz)    // 577 channels
#define ROW (Hsz * Csz)    // 6924 floats per (b,s) row
#define HALF 256           // (Wsz-1)/2

// Workspace layout (floats)
#define PSUM_SZ ((size_t)Bsz * Ssz)          // 8192
#define GACC_SZ ((size_t)Bsz * Gsz)          // 128
#define ROWSUM_SZ ((size_t)Bsz * Ssz * Csz)  // 4,727,808 (18.9 MB)

// k1a geometry: 2052 blocks x 256 thr x 9 iters == 4,727,808 exactly.
#define K1A_BLOCKS 2052
#define K1A_STRIDE (K1A_BLOCKS * 256u)       // 525,312
#define K1A_ITERS 9

// K1a: pure streaming h-sum, m13-copy-clone structure.
// rowsum[b,s,c] = sum_h probs[b,s,h,c]  (mask applied later in k1b).
// One basic block, no LDS, no barriers, low VGPR -> 32 waves/CU. Each
// element needs 12 independent coalesced scalar loads (consecutive lanes =
// consecutive addresses), staged into a register array before summing.
// This is the discriminating experiment for the ~2.4 TB/s plateau: every
// prior k1 mixed the gather with barriers/LDS/<=20 waves; this one has
// NOTHING but the gather.
__global__ __launch_bounds__(256) void k1a_hsum(
    const float* __restrict__ probs, float* __restrict__ rowsum)
{
    const unsigned o0 = blockIdx.x * 256u + threadIdx.x;
    #pragma unroll 2
    for (int it = 0; it < K1A_ITERS; ++it) {
        const unsigned o = o0 + (unsigned)it * K1A_STRIDE;
        const unsigned row = o / Csz;          // magic-mul, cheap
        const unsigned c = o - row * Csz;
        const float* __restrict__ p = probs + (size_t)row * ROW + c;

        float a[Hsz];
        #pragma unroll
        for (int h = 0; h < Hsz; ++h) a[h] = p[h * Csz];
        float v = 0.f;
        #pragma unroll
        for (int h = 0; h < Hsz; ++h) v += a[h];   // ascending h (ref order)
        rowsum[o] = v;
    }
}

// K1b: mask scale + global/local split + anti-diagonal window accumulation.
// Reads rowsum (19 MB) — trivial traffic. RPB2=16 rows/block, 512 blocks.
#define RPB2 16
#define WIN2 (RPB2 + Wsz - 1)   // 528
__global__ __launch_bounds__(256) void k1b_diag(
    const float* __restrict__ rowsum, const float* __restrict__ mask,
    float* __restrict__ psum, float* __restrict__ gacc)
{
    __shared__ float win[WIN2];    // 2,112 B
    const int t = threadIdx.x;
    const int row0 = blockIdx.x * RPB2;
    const int b = row0 / Ssz;
    float g = 0.f;                 // thread t<64: global channel t
    const bool c2ok = (t < Csz - 512);

    for (int w = t; w < WIN2; w += 256) win[w] = 0.f;
    __syncthreads();

    #pragma unroll 4
    for (int r = 0; r < RPB2; ++r) {
        const int row = row0 + r;
        const float* __restrict__ base = rowsum + (size_t)row * Csz;
        const float scale = (mask[row] < 0.f) ? 0.f : 1.f;

        const float v0 = base[t] * scale;            // channel t
        const float v1 = base[t + 256] * scale;      // channel t+256
        const float v2 = c2ok ? base[t + 512] * scale : 0.f;

        if (t < Gsz) g += v0;                                  // global channel
        else atomicAdd(&win[(t - Gsz) + r], v0);               // c-64 = t-64
        atomicAdd(&win[(t + 256 - Gsz) + r], v1);              // c-64 = t+192
        if (c2ok)
            atomicAdd(&win[(t + 512 - Gsz) + r], v2);          // c-64 = t+448
    }
    __syncthreads();

    // flush: psum[i_base + w] += win[w]
    const int i_base = (row0 - b * Ssz) - HALF;
    for (int w = t; w < WIN2; w += 256) {
        const int i = i_base + w;
        if (i >= 0 && i < Ssz) atomicAdd(&psum[b * Ssz + i], win[w]);
    }
    if (t < Gsz) atomicAdd(&gacc[b * Gsz + t], g);
}

// K4: fused scatter + per-batch max + scores + mask.
// grid = B, block = 1024. psum row staged in LDS; the 128-entry index-driven
// scatter is applied to the LDS copy, then reduce + write outputs.
__global__ __launch_bounds__(1024) void k4_final(
    const float* __restrict__ psum, const float* __restrict__ thr_p,
    const int* __restrict__ loc_b, const int* __restrict__ loc_i,
    const int* __restrict__ glob_b, const int* __restrict__ glob_i,
    const float* __restrict__ gacc, int n_idx,
    float* __restrict__ out)
{
    const int b = blockIdx.x;
    const int t = threadIdx.x;
    __shared__ float sp[Ssz];      // 16 KB
    const float* p = psum + (size_t)b * Ssz;

    for (int i = t; i < Ssz; i += 1024) sp[i] = p[i];
    __syncthreads();

    for (int k = t; k < n_idx; k += 1024)
        if (loc_b[k] == b)
            atomicAdd(&sp[loc_i[k]], gacc[glob_b[k] * Gsz + glob_i[k]]);
    __syncthreads();

    float m = -FLT_MAX;
    for (int i = t; i < Ssz; i += 1024) m = fmaxf(m, sp[i]);
    #pragma unroll
    for (int off = 32; off >= 1; off >>= 1) m = fmaxf(m, __shfl_down(m, off, 64));

    __shared__ float red[16];
    const int wave = t >> 6, lane = t & 63;
    if (lane == 0) red[wave] = m;
    __syncthreads();
    if (t == 0) {
        float mm = red[0];
        #pragma unroll
        for (int w = 1; w < 16; ++w) mm = fmaxf(mm, red[w]);
        red[0] = mm;
    }
    __syncthreads();
    const float mx = red[0];
    const float thr = fmaxf(1e-5f, thr_p[0]);

    for (int i = t; i < Ssz; i += 1024) {
        float sc = sp[i] / mx;                                    // divide: match ref rounding
        out[(size_t)Bsz * Ssz + (size_t)b * Ssz + i] = sc;        // scores (output 1)
        out[(size_t)b * Ssz + i] = (sc < thr) ? -10000.f : 0.f;   // mask (output 0)
    }
}

extern "C" void kernel_launch(void* const* d_in, const int* in_sizes, int n_in,
                              void* d_out, int out_size, void* d_ws, size_t ws_size,
                              hipStream_t stream)
{
    const float* mask  = (const float*)d_in[0];
    const float* probs = (const float*)d_in[1];
    const float* thr   = (const float*)d_in[2];
    // d_in[3] = max_num_global_attn_indices (hard-coded as Gsz)
    const int* loc_b  = (const int*)d_in[4];
    const int* loc_i  = (const int*)d_in[5];
    const int* glob_b = (const int*)d_in[6];
    const int* glob_i = (const int*)d_in[7];
    const int n_idx = in_sizes[4];

    float* psum   = (float*)d_ws;
    float* gacc   = psum + PSUM_SZ;
    float* rowsum = gacc + GACC_SZ;
    float* out    = (float*)d_out;

    // zero psum + gacc only (rowsum is pure-overwrite; ws poisoned 0xAA)
    (void)hipMemsetAsync(psum, 0, (PSUM_SZ + GACC_SZ) * sizeof(float), stream);

    k1a_hsum<<<dim3(K1A_BLOCKS), dim3(256), 0, stream>>>(probs, rowsum);
    k1b_diag<<<dim3(Bsz * Ssz / RPB2), dim3(256), 0, stream>>>(rowsum, mask, psum, gacc);
    k4_final<<<dim3(Bsz), dim3(1024), 0, stream>>>(psum, thr, loc_b, loc_i,
                                                   glob_b, glob_i, gacc, n_idx, out);
}

// Round 9
// 331.988 us; speedup vs baseline: 1.0879x; 1.0879x over previous
//
#include <hip/hip_runtime.h>
#include <float.h>

// Shapes (fixed by the problem)
#define Bsz 2
#define Ssz 4096
#define Hsz 12
#define Gsz 64
#define Wsz 513            // W_LOC
#define Csz (Gsz + Wsz)    // 577 channels
#define ROW (Hsz * Csz)    // 6924 floats per (b,s) row
#define ROWB (ROW * 4)     // 27,696 bytes (16B-aligned: 1731*16)
#define HALF 256           // (Wsz-1)/2
#define RPB 8              // rows per block -> 1024 blocks
#define WIN (RPB + Wsz - 1) // 520-wide output window per block

#define NCHUNK 27          // full 1024B gll chunks per row (27*1024 = 27648)
#define TAILOFF (NCHUNK * 1024) // 48B tail at 27648 (3 lanes x 16B)

// Workspace layout (floats)
#define PSUM_SZ ((size_t)Bsz * Ssz)   // 8192
#define GACC_SZ ((size_t)Bsz * Gsz)   // 128

typedef const __attribute__((address_space(1))) void* gptr_t;
typedef __attribute__((address_space(3))) void* lptr_t;

// Issue one full row (27,696 B) of global->LDS DMA. Every wave issues
// EXACTLY 7 global_load_lds instructions (7 vmcnt events) so the counted
// vmcnt(7) below is uniform:
//   waves 0-2: full chunks {w, w+4, ..., w+24}            (7 chunks)
//   wave 3   : full chunks {3, 7, 11, 15, 19, 23}          (6 chunks)
//              + the 48B tail, exec-masked to lanes 0-2    (1 instr)
__device__ __forceinline__ void stage_row(const char* rowbase, float* buf,
                                          int wave, int lane)
{
    char* lb = (char*)buf;
    #pragma unroll
    for (int j = 0; j < 7; ++j) {
        const int k = wave + 4 * j;
        if (k < NCHUNK)
            __builtin_amdgcn_global_load_lds(
                (gptr_t)(rowbase + k * 1024 + lane * 16),
                (lptr_t)(lb + k * 1024), 16, 0, 0);
    }
    if (wave == 3 && lane < 3)
        __builtin_amdgcn_global_load_lds(
            (gptr_t)(rowbase + TAILOFF + lane * 16),
            (lptr_t)(lb + TAILOFF), 16, 0, 0);
}

// K1: fused h-sum + anti-diagonal accumulation, gll double-buffer pipeline.
// Session finding (r0/r2/r4/r6/r8): five structurally independent k1s
// (LDS-staged copy, scalar direct, reg-array clause, this gll pipeline,
// pure streaming no-LDS/no-barrier) all plateau at ~2.3-2.4 TB/s for this
// read stream — the ceiling is the platform/pattern, not kernel structure.
// This variant is the session minimum (330.8 us total).
__global__ __launch_bounds__(256) void k1_fused(
    const float* __restrict__ probs, const float* __restrict__ mask,
    float* __restrict__ psum, float* __restrict__ gacc)
{
    __shared__ __align__(16) float bufA[ROW];   // 27,696 B
    __shared__ __align__(16) float bufB[ROW];   // 27,696 B
    __shared__ float win[WIN];                  //  2,080 B
    const int t = threadIdx.x;
    const int wave = t >> 6, lane = t & 63;
    const int row0 = blockIdx.x * RPB;
    const int b = row0 / Ssz;
    float g = 0.f;                 // thread t<64: global channel t
    const bool c2ok = (t < Csz - 512);

    for (int w = t; w < WIN; w += 256) win[w] = 0.f;

    // Preload + pin all mask scales now so the pipelined loop contains ZERO
    // extra vmcnt events (counted waits below must stay exact).
    float sc[RPB];
    #pragma unroll
    for (int r = 0; r < RPB; ++r) {
        sc[r] = (mask[row0 + r] < 0.f) ? 0.f : 1.f;
        asm volatile("" :: "v"(sc[r]));  // force materialization here
    }
    __syncthreads();                     // drains mask loads; covers win init

    const char* pb = (const char*)probs;
    stage_row(pb + (size_t)row0 * ROWB, bufA, wave, lane);   // prologue: 7/wave

    #pragma unroll
    for (int r = 0; r < RPB; ++r) {
        float* cur = (r & 1) ? bufB : bufA;
        float* nxt = (r & 1) ? bufA : bufB;

        if (r + 1 < RPB) {
            stage_row(pb + (size_t)(row0 + r + 1) * ROWB, nxt, wave, lane);
            asm volatile("s_waitcnt vmcnt(7)" ::: "memory"); // row r landed; r+1 in flight
        } else {
            asm volatile("s_waitcnt vmcnt(0)" ::: "memory"); // epilogue drain
        }
        __builtin_amdgcn_sched_barrier(0);
        __builtin_amdgcn_s_barrier();    // raw: no implicit vmcnt(0)

        // h-sum from LDS (lanes read consecutive addrs -> conflict-free).
        // Thread t owns channels {t, t+256, t+512<577}.
        float v0 = 0.f, v1 = 0.f, v2 = 0.f;
        #pragma unroll
        for (int h = 0; h < Hsz; ++h) {
            v0 += cur[h * Csz + t];
            v1 += cur[h * Csz + t + 256];
        }
        if (c2ok) {
            #pragma unroll
            for (int h = 0; h < Hsz; ++h) v2 += cur[h * Csz + t + 512];
        }
        v0 *= sc[r]; v1 *= sc[r]; v2 *= sc[r];

        if (t < Gsz) g += v0;                                  // global channel
        else atomicAdd(&win[(t - Gsz) + r], v0);               // c-64 = t-64
        atomicAdd(&win[(t + 256 - Gsz) + r], v1);              // c-64 = t+192
        if (c2ok)
            atomicAdd(&win[(t + 512 - Gsz) + r], v2);          // c-64 = t+448

        __builtin_amdgcn_s_barrier();    // protect cur before it is restaged
    }
    __syncthreads();

    // flush the 520-wide window: i = (s0 - 256) + w
    const int i_base = (row0 - b * Ssz) - HALF;
    for (int w = t; w < WIN; w += 256) {
        const int i = i_base + w;
        if (i >= 0 && i < Ssz) atomicAdd(&psum[b * Ssz + i], win[w]);
    }
    if (t < Gsz) atomicAdd(&gacc[b * Gsz + t], g);
}

// K4: fused scatter + per-batch max + scores + mask.
// grid = B, block = 1024 (16 waves). psum row staged in LDS; the 128-entry
// index-driven scatter is applied to the LDS copy (block b only touches its
// own row), then reduce + write outputs.
__global__ __launch_bounds__(1024) void k4_final(
    const float* __restrict__ psum, const float* __restrict__ thr_p,
    const int* __restrict__ loc_b, const int* __restrict__ loc_i,
    const int* __restrict__ glob_b, const int* __restrict__ glob_i,
    const float* __restrict__ gacc, int n_idx,
    float* __restrict__ out)
{
    const int b = blockIdx.x;
    const int t = threadIdx.x;
    __shared__ float sp[Ssz];      // 16 KB
    const float* p = psum + (size_t)b * Ssz;

    for (int i = t; i < Ssz; i += 1024) sp[i] = p[i];
    __syncthreads();

    // honor the index arrays: psum[loc_b,loc_i] += gacc[glob_b,glob_i]
    for (int k = t; k < n_idx; k += 1024)
        if (loc_b[k] == b)
            atomicAdd(&sp[loc_i[k]], gacc[glob_b[k] * Gsz + glob_i[k]]);
    __syncthreads();

    float m = -FLT_MAX;
    for (int i = t; i < Ssz; i += 1024) m = fmaxf(m, sp[i]);
    #pragma unroll
    for (int off = 32; off >= 1; off >>= 1) m = fmaxf(m, __shfl_down(m, off, 64));

    __shared__ float red[16];
    const int wave = t >> 6, lane = t & 63;
    if (lane == 0) red[wave] = m;
    __syncthreads();
    if (t == 0) {
        float mm = red[0];
        #pragma unroll
        for (int w = 1; w < 16; ++w) mm = fmaxf(mm, red[w]);
        red[0] = mm;
    }
    __syncthreads();
    const float mx = red[0];
    const float thr = fmaxf(1e-5f, thr_p[0]);

    for (int i = t; i < Ssz; i += 1024) {
        float sc = sp[i] / mx;                                    // divide: match ref rounding
        out[(size_t)Bsz * Ssz + (size_t)b * Ssz + i] = sc;        // scores (output 1)
        out[(size_t)b * Ssz + i] = (sc < thr) ? -10000.f : 0.f;   // mask (output 0)
    }
}

extern "C" void kernel_launch(void* const* d_in, const int* in_sizes, int n_in,
                              void* d_out, int out_size, void* d_ws, size_t ws_size,
                              hipStream_t stream)
{
    const float* mask  = (const float*)d_in[0];
    const float* probs = (const float*)d_in[1];
    const float* thr   = (const float*)d_in[2];
    // d_in[3] = max_num_global_attn_indices (hard-coded as Gsz)
    const int* loc_b  = (const int*)d_in[4];
    const int* loc_i  = (const int*)d_in[5];
    const int* glob_b = (const int*)d_in[6];
    const int* glob_i = (const int*)d_in[7];
    const int n_idx = in_sizes[4];

    float* psum = (float*)d_ws;
    float* gacc = psum + PSUM_SZ;
    float* out  = (float*)d_out;

    // zero psum + gacc (ws is poisoned 0xAA before every launch)
    (void)hipMemsetAsync(psum, 0, (PSUM_SZ + GACC_SZ) * sizeof(float), stream);

    k1_fused<<<dim3(Bsz * Ssz / RPB), dim3(256), 0, stream>>>(probs, mask, psum, gacc);
    k4_final<<<dim3(Bsz), dim3(1024), 0, stream>>>(psum, thr, loc_b, loc_i,
                                                   glob_b, glob_i, gacc, n_idx, out);
}